// Round 1
// baseline (182.509 us; speedup 1.0000x reference)
//
#include <hip/hip_runtime.h>

typedef short short8 __attribute__((ext_vector_type(8)));
typedef short short4v __attribute__((ext_vector_type(4)));
typedef float float4v __attribute__((ext_vector_type(4)));
typedef float f32x4 __attribute__((ext_vector_type(4)));

#define NEG_HUGE (-1e30f)

__device__ __forceinline__ unsigned short f2bf(float f) {
  union { float f; unsigned u; } v; v.f = f;
  unsigned r = v.u + 0x7fffu + ((v.u >> 16) & 1u);
  return (unsigned short)(r >> 16);
}

#define MFMA16(a, b, c) __builtin_amdgcn_mfma_f32_16x16x32_bf16((a), (b), (c), 0, 0, 0)

// ---------------------------------------------------------------------------
// Kernel 0: W [1024][64] fp32 (x3) -> Wt [3][64][1024] bf16 (transposed, n-major)
// ---------------------------------------------------------------------------
__global__ __launch_bounds__(256) void wtrans_kernel(
    const float* __restrict__ Wk, const float* __restrict__ Wq,
    const float* __restrict__ Wv, unsigned short* __restrict__ Wt) {
  int mat = blockIdx.x >> 4, kb = blockIdx.x & 15;
  const float* W = (mat == 0) ? Wk : ((mat == 1) ? Wq : Wv);
  __shared__ float tile[64][65];
  int tid = threadIdx.x;
  int n = tid & 63, k0 = tid >> 6;
#pragma unroll
  for (int i = 0; i < 16; i++) {
    int k = i * 4 + k0;
    tile[k][n] = W[(kb * 64 + k) * 64 + n];
  }
  __syncthreads();
  int n2 = tid >> 2, c = tid & 3;
  unsigned short tmp[16];
#pragma unroll
  for (int j = 0; j < 16; j++) tmp[j] = f2bf(tile[c * 16 + j][n2]);
  unsigned short* dst = Wt + (mat * 64 + n2) * 1024 + kb * 64 + c * 16;
  *(short8*)dst = *(short8*)tmp;
  *(short8*)(dst + 8) = *(short8*)(tmp + 8);
}

// ---------------------------------------------------------------------------
// Kernel 1: projection. x[16384][1024] fp32 @ Wt[3][64][1024] bf16
//   -> Kb/Qb/Vb [16384][64] bf16.  BM=64 (wave=16 rows), BN=192, BK=32.
// ---------------------------------------------------------------------------
__global__ __launch_bounds__(256) void proj_kernel(
    const float* __restrict__ x, const unsigned short* __restrict__ Wt,
    unsigned short* __restrict__ Kb, unsigned short* __restrict__ Qb,
    unsigned short* __restrict__ Vb) {
  __shared__ unsigned short x_lds[64][40];   // pad 40 -> 2-way-free b128 reads
  __shared__ unsigned short w_lds[192][40];
  int tid = threadIdx.x;
  int w = tid >> 6, lane = tid & 63;
  int g = lane >> 4, r = lane & 15;
  int row0 = blockIdx.x * 64;

  f32x4 acc[12];
#pragma unroll
  for (int nf = 0; nf < 12; nf++) acc[nf] = (f32x4){0.f, 0.f, 0.f, 0.f};

  for (int k0 = 0; k0 < 1024; k0 += 32) {
    // stage x tile 64x32 fp32 -> bf16
#pragma unroll
    for (int i = 0; i < 2; i++) {
      int idx = tid + i * 256;
      int xr = idx >> 3, c4 = idx & 7;
      float4v v = *(const float4v*)&x[(size_t)(row0 + xr) * 1024 + k0 + c4 * 4];
      unsigned short t4[4];
      t4[0] = f2bf(v[0]); t4[1] = f2bf(v[1]); t4[2] = f2bf(v[2]); t4[3] = f2bf(v[3]);
      *(short4v*)&x_lds[xr][c4 * 4] = *(short4v*)t4;
    }
    // stage Wt tile 192 x 32 bf16 (already n-major)
#pragma unroll
    for (int i = 0; i < 3; i++) {
      int idx = tid + i * 256;
      int wn = idx >> 2, c = idx & 3;
      *(short8*)&w_lds[wn][c * 8] = *(const short8*)&Wt[wn * 1024 + k0 + c * 8];
    }
    __syncthreads();
    short8 a = *(short8*)&x_lds[w * 16 + r][g * 8];
#pragma unroll
    for (int nf = 0; nf < 12; nf++) {
      short8 bf = *(short8*)&w_lds[nf * 16 + r][g * 8];
      acc[nf] = MFMA16(a, bf, acc[nf]);
    }
    __syncthreads();
  }
  // epilogue: D row = 4*g + reg (within wave's 16), col = 16*nf + r
#pragma unroll
  for (int nf = 0; nf < 12; nf++) {
    int col = nf * 16 + r;
    int mat = col >> 6, h = col & 63;
    unsigned short* dst = (mat == 0) ? Kb : ((mat == 1) ? Qb : Vb);
#pragma unroll
    for (int reg = 0; reg < 4; reg++) {
      int grow = row0 + w * 16 + g * 4 + reg;
      dst[(size_t)grow * 64 + h] = f2bf(acc[nf][reg]);
    }
  }
}

// ---------------------------------------------------------------------------
// Kernel 2: causal flash attention. 1 block = 2 paired q-tiles of 32 rows
// (balanced). 4 waves split kv tiles (t%4==w) with private (m,l,O); LDS merge.
// ---------------------------------------------------------------------------
__global__ __launch_bounds__(256) void attn_kernel(
    const unsigned short* __restrict__ Kb, const unsigned short* __restrict__ Qb,
    const unsigned short* __restrict__ Vb, float* __restrict__ out) {
  // LDS: phase A (kv loop): per-wave Vt[64][72] (9216B) + P[32][72] (4608B)
  //      phase B (merge):   O_l[4][32][64] f32 (32KB) + stats[4][32][2] (1KB)
  __shared__ __align__(16) char smem[55296];
  int tid = threadIdx.x;
  int w = tid >> 6, lane = tid & 63;
  int g = lane >> 4, r = lane & 15;
  int b = blockIdx.x >> 6, pi = blockIdx.x & 63;
  const unsigned short* Kp = Kb + (size_t)b * 4096 * 64;
  const unsigned short* Qp = Qb + (size_t)b * 4096 * 64;
  const unsigned short* Vp = Vb + (size_t)b * 4096 * 64;
  unsigned short* vt = (unsigned short*)(smem + w * 9216);
  unsigned short* pl = (unsigned short*)(smem + 36864 + w * 4608);
  float* O_l = (float*)smem;
  float* st_l = (float*)(smem + 32768);

  for (int qi = 0; qi < 2; qi++) {
    int qt = qi ? (127 - pi) : pi;
    int qabs = qt * 32;

    // hoist Q fragments: A[i=q(l&15)+16mf][k=h=32ks+8g+j]
    short8 qa[2][2];
#pragma unroll
    for (int mf = 0; mf < 2; mf++)
#pragma unroll
      for (int ks = 0; ks < 2; ks++)
        qa[mf][ks] = *(const short8*)&Qp[(size_t)(qabs + mf * 16 + r) * 64 + ks * 32 + g * 8];

    float m_st[2][4], l_st[2][4];
    f32x4 o[2][4];
#pragma unroll
    for (int mf = 0; mf < 2; mf++)
#pragma unroll
      for (int reg = 0; reg < 4; reg++) { m_st[mf][reg] = NEG_HUGE; l_st[mf][reg] = 0.f; }
#pragma unroll
    for (int mf = 0; mf < 2; mf++)
#pragma unroll
      for (int nfh = 0; nfh < 4; nfh++) o[mf][nfh] = (f32x4){0.f, 0.f, 0.f, 0.f};

    int ntiles = (qabs >> 6) + 1;
    for (int t = w; t < ntiles; t += 4) {
      int kvb = t * 64;
      // ---- stage V transposed: vt[h][kv], j-swizzled scalar writes ----
      {
        int vrl = lane >> 3, c = lane & 7;
#pragma unroll
        for (int i = 0; i < 8; i++) {
          int vr = i * 8 + vrl;
          short8 vv = *(const short8*)&Vp[(size_t)(kvb + vr) * 64 + c * 8];
#pragma unroll
          for (int j0 = 0; j0 < 8; j0++) {
            int j = (j0 + c) & 7;
            vt[(c * 8 + j) * 72 + vr] = (unsigned short)vv[j];
          }
        }
      }
      // ---- S = Q K^T ----
      f32x4 s[2][4];
#pragma unroll
      for (int mf = 0; mf < 2; mf++)
#pragma unroll
        for (int nf = 0; nf < 4; nf++) s[mf][nf] = (f32x4){0.f, 0.f, 0.f, 0.f};
#pragma unroll
      for (int ks = 0; ks < 2; ks++)
#pragma unroll
        for (int nf = 0; nf < 4; nf++) {
          short8 kf = *(const short8*)&Kp[(size_t)(kvb + nf * 16 + r) * 64 + ks * 32 + g * 8];
          s[0][nf] = MFMA16(qa[0][ks], kf, s[0][nf]);
          s[1][nf] = MFMA16(qa[1][ks], kf, s[1][nf]);
        }
      // ---- scale + causal mask + row max ----
      float mx[2][4], alpha[2][4];
#pragma unroll
      for (int mf = 0; mf < 2; mf++)
#pragma unroll
        for (int reg = 0; reg < 4; reg++) {
          int q = qabs + mf * 16 + g * 4 + reg;
          float m0 = NEG_HUGE;
#pragma unroll
          for (int nf = 0; nf < 4; nf++) {
            int kv = kvb + nf * 16 + r;
            float val = s[mf][nf][reg] * 0.125f;
            val = (kv <= q) ? val : NEG_HUGE;
            s[mf][nf][reg] = val;
            m0 = fmaxf(m0, val);
          }
          mx[mf][reg] = m0;
        }
#pragma unroll
      for (int mf = 0; mf < 2; mf++)
#pragma unroll
        for (int reg = 0; reg < 4; reg++) {
          float m0 = mx[mf][reg];
          m0 = fmaxf(m0, __shfl_xor(m0, 1));
          m0 = fmaxf(m0, __shfl_xor(m0, 2));
          m0 = fmaxf(m0, __shfl_xor(m0, 4));
          m0 = fmaxf(m0, __shfl_xor(m0, 8));
          float mn = fmaxf(m_st[mf][reg], m0);
          alpha[mf][reg] = __expf(m_st[mf][reg] - mn);
          m_st[mf][reg] = mn;
        }
      // ---- P = exp(S - m), row sums, write P to LDS (bf16) ----
      float rs[2][4] = {};
#pragma unroll
      for (int mf = 0; mf < 2; mf++)
#pragma unroll
        for (int nf = 0; nf < 4; nf++)
#pragma unroll
          for (int reg = 0; reg < 4; reg++) {
            float p = __expf(s[mf][nf][reg] - m_st[mf][reg]);
            rs[mf][reg] += p;
            pl[(mf * 16 + g * 4 + reg) * 72 + nf * 16 + r] = f2bf(p);
          }
#pragma unroll
      for (int mf = 0; mf < 2; mf++)
#pragma unroll
        for (int reg = 0; reg < 4; reg++) {
          float s0 = rs[mf][reg];
          s0 += __shfl_xor(s0, 1);
          s0 += __shfl_xor(s0, 2);
          s0 += __shfl_xor(s0, 4);
          s0 += __shfl_xor(s0, 8);
          l_st[mf][reg] = l_st[mf][reg] * alpha[mf][reg] + s0;
#pragma unroll
          for (int nfh = 0; nfh < 4; nfh++) o[mf][nfh][reg] *= alpha[mf][reg];
        }
      asm volatile("s_waitcnt lgkmcnt(0)" ::: "memory");
      // ---- O += P V ----
#pragma unroll
      for (int ks2 = 0; ks2 < 2; ks2++) {
        short8 pa0 = *(const short8*)&pl[(0 + r) * 72 + ks2 * 32 + g * 8];
        short8 pa1 = *(const short8*)&pl[(16 + r) * 72 + ks2 * 32 + g * 8];
#pragma unroll
        for (int nfh = 0; nfh < 4; nfh++) {
          short8 vf = *(const short8*)&vt[(nfh * 16 + r) * 72 + ks2 * 32 + g * 8];
          o[0][nfh] = MFMA16(pa0, vf, o[0][nfh]);
          o[1][nfh] = MFMA16(pa1, vf, o[1][nfh]);
        }
      }
    }
    // ---- cross-wave merge ----
    __syncthreads();
#pragma unroll
    for (int mf = 0; mf < 2; mf++)
#pragma unroll
      for (int nfh = 0; nfh < 4; nfh++)
#pragma unroll
        for (int reg = 0; reg < 4; reg++)
          O_l[(w * 32 + mf * 16 + g * 4 + reg) * 64 + nfh * 16 + r] = o[mf][nfh][reg];
    if (r == 0) {
#pragma unroll
      for (int mf = 0; mf < 2; mf++)
#pragma unroll
        for (int reg = 0; reg < 4; reg++) {
          int rr = mf * 16 + g * 4 + reg;
          st_l[(w * 32 + rr) * 2 + 0] = m_st[mf][reg];
          st_l[(w * 32 + rr) * 2 + 1] = l_st[mf][reg];
        }
    }
    __syncthreads();
    {
      int row = tid >> 3, cg = tid & 7;
      float mw[4], lw[4];
#pragma unroll
      for (int ww = 0; ww < 4; ww++) {
        mw[ww] = st_l[(ww * 32 + row) * 2 + 0];
        lw[ww] = st_l[(ww * 32 + row) * 2 + 1];
      }
      float mstar = fmaxf(fmaxf(mw[0], mw[1]), fmaxf(mw[2], mw[3]));
      float sc[4], lstar = 0.f;
#pragma unroll
      for (int ww = 0; ww < 4; ww++) { sc[ww] = __expf(mw[ww] - mstar); lstar += sc[ww] * lw[ww]; }
      float inv = 1.0f / lstar;
#pragma unroll
      for (int cc = 0; cc < 8; cc++) {
        int col = cg * 8 + cc;
        float a0 = 0.f;
#pragma unroll
        for (int ww = 0; ww < 4; ww++) a0 += sc[ww] * O_l[(ww * 32 + row) * 64 + col];
        out[((size_t)b * 4096 + qabs + row) * 64 + col] = a0 * inv;
      }
    }
    __syncthreads();
  }
}

// ---------------------------------------------------------------------------
extern "C" void kernel_launch(void* const* d_in, const int* in_sizes, int n_in,
                              void* d_out, int out_size, void* d_ws, size_t ws_size,
                              hipStream_t stream) {
  (void)in_sizes; (void)n_in; (void)out_size; (void)ws_size;
  const float* x  = (const float*)d_in[0];
  const float* Wk = (const float*)d_in[1];
  const float* Wq = (const float*)d_in[2];
  const float* Wv = (const float*)d_in[3];
  float* out = (float*)d_out;
  char* ws = (char*)d_ws;

  unsigned short* Wt = (unsigned short*)ws;                       // 3*64*1024*2 = 384KB
  unsigned short* Kb = (unsigned short*)(ws + (512u << 10));      // 2MB
  unsigned short* Qb = (unsigned short*)(ws + (512u << 10) + (2u << 20));
  unsigned short* Vb = (unsigned short*)(ws + (512u << 10) + (4u << 20));

  wtrans_kernel<<<48, 256, 0, stream>>>(Wk, Wq, Wv, Wt);
  proj_kernel<<<256, 256, 0, stream>>>(x, Wt, Kb, Qb, Vb);
  attn_kernel<<<256, 256, 0, stream>>>(Kb, Qb, Vb, out);
}

// Round 3
// 98.653 us; speedup vs baseline: 1.8500x; 1.8500x over previous
//
#include <hip/hip_runtime.h>
#include <hip/hip_bf16.h>

typedef short short8 __attribute__((ext_vector_type(8)));
typedef short short4v __attribute__((ext_vector_type(4)));
typedef float float4v __attribute__((ext_vector_type(4)));
typedef float f32x4 __attribute__((ext_vector_type(4)));

#define NEG_HUGE (-1e30f)
#define QK_SCALE 0.1803368801111204f  /* 0.125 * log2(e) */

__device__ __forceinline__ unsigned short f2bf(float f) {
  union { __hip_bfloat16 h; unsigned short u; } c;
  c.h = __float2bfloat16(f);
  return c.u;
}

#define MFMA16(a, b, c) __builtin_amdgcn_mfma_f32_16x16x32_bf16((a), (b), (c), 0, 0, 0)

// ---------------------------------------------------------------------------
// Kernel 0: W [1024][64] fp32 (x3) -> Wt [3][64][1024] bf16 (transposed).
// Wq additionally scaled by 0.125*log2(e) so attn works in exp2 domain.
// ---------------------------------------------------------------------------
__global__ __launch_bounds__(256) void wtrans_kernel(
    const float* __restrict__ Wk, const float* __restrict__ Wq,
    const float* __restrict__ Wv, unsigned short* __restrict__ Wt) {
  int mat = blockIdx.x >> 4, kb = blockIdx.x & 15;
  const float* W = (mat == 0) ? Wk : ((mat == 1) ? Wq : Wv);
  float qscale = (mat == 1) ? QK_SCALE : 1.0f;
  __shared__ float tile[64][65];
  int tid = threadIdx.x;
  int n = tid & 63, k0 = tid >> 6;
#pragma unroll
  for (int i = 0; i < 16; i++) {
    int k = i * 4 + k0;
    tile[k][n] = W[(kb * 64 + k) * 64 + n];
  }
  __syncthreads();
  int n2 = tid >> 2, c = tid & 3;
  unsigned short tmp[16];
#pragma unroll
  for (int j = 0; j < 16; j++) tmp[j] = f2bf(tile[c * 16 + j][n2] * qscale);
  unsigned short* dst = Wt + (mat * 64 + n2) * 1024 + kb * 64 + c * 16;
  *(short8*)dst = *(short8*)tmp;
  *(short8*)(dst + 8) = *(short8*)(tmp + 8);
}

// ---------------------------------------------------------------------------
// Kernel 1: projection. x[16384][1024] fp32 @ Wt[3][64][1024] bf16
//   -> Kb/Qb [16384][64] bf16 (row-major), Vt [4][64][4096] bf16 (transposed).
// 512 threads = 8 waves: wm in 0..3 (16 rows), wn in 0..1 (96 cols).
// ---------------------------------------------------------------------------
__global__ __launch_bounds__(512) void proj_kernel(
    const float* __restrict__ x, const unsigned short* __restrict__ Wt,
    unsigned short* __restrict__ Kb, unsigned short* __restrict__ Qb,
    unsigned short* __restrict__ Vt) {
  __shared__ unsigned short x_lds[64][40];
  __shared__ unsigned short w_lds[192][40];
  int tid = threadIdx.x;
  int w = tid >> 6, lane = tid & 63;
  int wm = w & 3, wn = w >> 2;
  int g = lane >> 4, r = lane & 15;
  int row0 = blockIdx.x * 64;

  f32x4 acc[6];
#pragma unroll
  for (int nf = 0; nf < 6; nf++) acc[nf] = (f32x4){0.f, 0.f, 0.f, 0.f};

  for (int k0 = 0; k0 < 1024; k0 += 32) {
    // stage x tile 64x32 fp32 -> bf16 (one float4 per thread)
    {
      int xr = tid >> 3, c4 = tid & 7;
      float4v v = *(const float4v*)&x[(size_t)(row0 + xr) * 1024 + k0 + c4 * 4];
      unsigned short t4[4];
      t4[0] = f2bf(v[0]); t4[1] = f2bf(v[1]); t4[2] = f2bf(v[2]); t4[3] = f2bf(v[3]);
      *(short4v*)&x_lds[xr][c4 * 4] = *(short4v*)t4;
    }
    // stage Wt tile 192x32 bf16 (768 short8 loads over 512 threads)
#pragma unroll
    for (int i = 0; i < 2; i++) {
      int idx = tid + i * 512;
      if (idx < 768) {
        int wr = idx >> 2, c = idx & 3;
        *(short8*)&w_lds[wr][c * 8] = *(const short8*)&Wt[wr * 1024 + k0 + c * 8];
      }
    }
    __syncthreads();
    short8 a = *(short8*)&x_lds[wm * 16 + r][g * 8];
#pragma unroll
    for (int nf = 0; nf < 6; nf++) {
      short8 bf = *(short8*)&w_lds[wn * 96 + nf * 16 + r][g * 8];
      acc[nf] = MFMA16(a, bf, acc[nf]);
    }
    __syncthreads();
  }
  // epilogue: D row = row0 + wm*16 + g*4 + reg, col = wn*96 + nf*16 + r
#pragma unroll
  for (int nf = 0; nf < 6; nf++) {
    int col = wn * 96 + nf * 16 + r;
    if (col < 128) {
      int mat = col >> 6, h = col & 63;
      unsigned short* dst = (mat == 0) ? Kb : Qb;
#pragma unroll
      for (int reg = 0; reg < 4; reg++) {
        int grow = row0 + wm * 16 + g * 4 + reg;
        dst[(size_t)grow * 64 + h] = f2bf(acc[nf][reg]);
      }
    } else {
      int h = col & 63;
      int grow0 = row0 + wm * 16 + g * 4;
      unsigned short t4[4];
#pragma unroll
      for (int reg = 0; reg < 4; reg++) t4[reg] = f2bf(acc[nf][reg]);
      size_t off = ((size_t)(grow0 >> 12) * 64 + h) * 4096 + (grow0 & 4095);
      *(short4v*)&Vt[off] = *(short4v*)t4;
    }
  }
}

// ---------------------------------------------------------------------------
// Kernel 2: causal flash attention v3 (swapped QK^T).
// S^T = mfma(A=K, B=Q): lane (g,r) holds S^T[kv=nf*16+g*4+reg][q=r].
// Softmax reduce = shfl_xor 16/32. P written row-major [q][kv] via b64
// (lane holds 4 consecutive kv), PV A-frag read back via b128. V direct
// from global Vt. 4 waves kv-split (t%4==w), private (m,l,O), LDS merge.
// ---------------------------------------------------------------------------
__global__ __launch_bounds__(256, 2) void attn_kernel(
    const unsigned short* __restrict__ Kb, const unsigned short* __restrict__ Qb,
    const unsigned short* __restrict__ VtB, float* __restrict__ out) {
  __shared__ unsigned short pls[4][32][72];   // per-wave P, row-major [q][kv]
  __shared__ float O_l[4][32][64];
  __shared__ float st_l[4][32][2];
  int tid = threadIdx.x;
  int w = tid >> 6, lane = tid & 63;
  int g = lane >> 4, r = lane & 15;
  int bi = blockIdx.x;
  int b = bi & 3, iq = bi >> 2;
  int qt = (iq & 1) ? (127 - (iq >> 1)) : (iq >> 1);
  int qabs = qt * 32;
  const unsigned short* Kp = Kb + (size_t)b * 4096 * 64;
  const unsigned short* Qp = Qb + (size_t)b * 4096 * 64;
  const unsigned short* Vp = VtB + (size_t)b * 64 * 4096;

  // hoist Q fragments (B operand): B[n=q=mf*16+r][k=h=ks*32+g*8+j]
  short8 qa[2][2];
#pragma unroll
  for (int mf = 0; mf < 2; mf++)
#pragma unroll
    for (int ks = 0; ks < 2; ks++)
      qa[mf][ks] = *(const short8*)&Qp[(size_t)(qabs + mf * 16 + r) * 64 + ks * 32 + g * 8];

  float m_st[2] = {NEG_HUGE, NEG_HUGE};
  float l_st[2] = {0.f, 0.f};
  f32x4 o[2][4];
#pragma unroll
  for (int mf = 0; mf < 2; mf++)
#pragma unroll
    for (int nfh = 0; nfh < 4; nfh++) o[mf][nfh] = (f32x4){0.f, 0.f, 0.f, 0.f};

  int ntiles = (qabs >> 6) + 1;
  for (int t = w; t < ntiles; t += 4) {
    int kvb = t << 6;
    // ---- V B-fragments direct from global Vt ----
    short8 vf[2][4];
#pragma unroll
    for (int ks = 0; ks < 2; ks++)
#pragma unroll
      for (int nfh = 0; nfh < 4; nfh++)
        vf[ks][nfh] = *(const short8*)&Vp[(size_t)(nfh * 16 + r) * 4096 + kvb + ks * 32 + g * 8];
    // ---- K A-fragments: A[row=kv=nf*16+r][k=h] ----
    short8 kf[2][4];
#pragma unroll
    for (int ks = 0; ks < 2; ks++)
#pragma unroll
      for (int nf = 0; nf < 4; nf++)
        kf[ks][nf] = *(const short8*)&Kp[(size_t)(kvb + nf * 16 + r) * 64 + ks * 32 + g * 8];
    // ---- S^T = K Q^T (swapped) ----
    f32x4 s[4][2];
#pragma unroll
    for (int nf = 0; nf < 4; nf++)
#pragma unroll
      for (int mf = 0; mf < 2; mf++) s[nf][mf] = (f32x4){0.f, 0.f, 0.f, 0.f};
#pragma unroll
    for (int ks = 0; ks < 2; ks++)
#pragma unroll
      for (int nf = 0; nf < 4; nf++) {
        s[nf][0] = MFMA16(kf[ks][nf], qa[0][ks], s[nf][0]);
        s[nf][1] = MFMA16(kf[ks][nf], qa[1][ks], s[nf][1]);
      }
    // ---- causal mask (only partial tiles) ----
    if (kvb + 63 > qabs) {
#pragma unroll
      for (int mf = 0; mf < 2; mf++) {
        int q = qabs + mf * 16 + r;
#pragma unroll
        for (int nf = 0; nf < 4; nf++)
#pragma unroll
          for (int reg = 0; reg < 4; reg++) {
            int kv = kvb + nf * 16 + g * 4 + reg;
            if (kv > q) s[nf][mf][reg] = NEG_HUGE;
          }
      }
    }
    // ---- row max (q=r fixed per lane; kv over nf,reg in-lane + g cross-lane) ----
    float alpha[2];
#pragma unroll
    for (int mf = 0; mf < 2; mf++) {
      float m0 = NEG_HUGE;
#pragma unroll
      for (int nf = 0; nf < 4; nf++) {
        float a2 = fmaxf(fmaxf(s[nf][mf][0], s[nf][mf][1]),
                         fmaxf(s[nf][mf][2], s[nf][mf][3]));
        m0 = fmaxf(m0, a2);
      }
      m0 = fmaxf(m0, __shfl_xor(m0, 16));
      m0 = fmaxf(m0, __shfl_xor(m0, 32));
      float mn = fmaxf(m_st[mf], m0);
      alpha[mf] = exp2f(m_st[mf] - mn);
      m_st[mf] = mn;
    }
    // ---- P = exp2(S-m); pack bf16; b64 write rows [q][kv]; partial sums ----
    float rs[2] = {0.f, 0.f};
#pragma unroll
    for (int mf = 0; mf < 2; mf++)
#pragma unroll
      for (int nf = 0; nf < 4; nf++) {
        unsigned short t4[4];
#pragma unroll
        for (int reg = 0; reg < 4; reg++) {
          float p = exp2f(s[nf][mf][reg] - m_st[mf]);
          rs[mf] += p;
          t4[reg] = f2bf(p);
        }
        *(short4v*)&pls[w][mf * 16 + r][nf * 16 + g * 4] = *(short4v*)t4;
      }
#pragma unroll
    for (int mf = 0; mf < 2; mf++) {
      float s0 = rs[mf];
      s0 += __shfl_xor(s0, 16);
      s0 += __shfl_xor(s0, 32);
      l_st[mf] = l_st[mf] * alpha[mf] + s0;
    }
    // ---- rescale O (alpha indexed by q=g*4+reg via shuffle from lanes 0..15) ----
#pragma unroll
    for (int mf = 0; mf < 2; mf++)
#pragma unroll
      for (int reg = 0; reg < 4; reg++) {
        float av = __shfl(alpha[mf], g * 4 + reg);
#pragma unroll
        for (int nfh = 0; nfh < 4; nfh++) o[mf][nfh][reg] *= av;
      }
    // ---- P A-fragments via b128, then O += P V ----
    short8 pa[2][2];
#pragma unroll
    for (int mf = 0; mf < 2; mf++)
#pragma unroll
      for (int ks = 0; ks < 2; ks++)
        pa[mf][ks] = *(short8*)&pls[w][mf * 16 + r][ks * 32 + g * 8];
#pragma unroll
    for (int ks = 0; ks < 2; ks++)
#pragma unroll
      for (int nfh = 0; nfh < 4; nfh++) {
        o[0][nfh] = MFMA16(pa[0][ks], vf[ks][nfh], o[0][nfh]);
        o[1][nfh] = MFMA16(pa[1][ks], vf[ks][nfh], o[1][nfh]);
      }
  }
  // ---- cross-wave merge ----
  __syncthreads();
#pragma unroll
  for (int mf = 0; mf < 2; mf++)
#pragma unroll
    for (int nfh = 0; nfh < 4; nfh++)
#pragma unroll
      for (int reg = 0; reg < 4; reg++)
        O_l[w][mf * 16 + g * 4 + reg][nfh * 16 + r] = o[mf][nfh][reg];
  if (g == 0) {
#pragma unroll
    for (int mf = 0; mf < 2; mf++) {
      st_l[w][mf * 16 + r][0] = m_st[mf];
      st_l[w][mf * 16 + r][1] = l_st[mf];
    }
  }
  __syncthreads();
  {
    int row = tid >> 3, cg = tid & 7;
    float mw[4], lw[4];
#pragma unroll
    for (int ww = 0; ww < 4; ww++) {
      mw[ww] = st_l[ww][row][0];
      lw[ww] = st_l[ww][row][1];
    }
    float mstar = fmaxf(fmaxf(mw[0], mw[1]), fmaxf(mw[2], mw[3]));
    float sc[4], lstar = 0.f;
#pragma unroll
    for (int ww = 0; ww < 4; ww++) { sc[ww] = exp2f(mw[ww] - mstar); lstar += sc[ww] * lw[ww]; }
    float inv = 1.0f / lstar;
    int qabs2 = qt * 32;
#pragma unroll
    for (int cc = 0; cc < 8; cc++) {
      int col = cg * 8 + cc;
      float a0 = 0.f;
#pragma unroll
      for (int ww = 0; ww < 4; ww++) a0 += sc[ww] * O_l[ww][row][col];
      out[((size_t)b * 4096 + qabs2 + row) * 64 + col] = a0 * inv;
    }
  }
}

// ---------------------------------------------------------------------------
extern "C" void kernel_launch(void* const* d_in, const int* in_sizes, int n_in,
                              void* d_out, int out_size, void* d_ws, size_t ws_size,
                              hipStream_t stream) {
  (void)in_sizes; (void)n_in; (void)out_size; (void)ws_size;
  const float* x  = (const float*)d_in[0];
  const float* Wk = (const float*)d_in[1];
  const float* Wq = (const float*)d_in[2];
  const float* Wv = (const float*)d_in[3];
  float* out = (float*)d_out;
  char* ws = (char*)d_ws;

  unsigned short* Wt = (unsigned short*)ws;                       // 384KB
  unsigned short* Kb = (unsigned short*)(ws + (512u << 10));      // 2MB
  unsigned short* Qb = (unsigned short*)(ws + (512u << 10) + (2u << 20));
  unsigned short* Vt = (unsigned short*)(ws + (512u << 10) + (4u << 20));

  wtrans_kernel<<<48, 256, 0, stream>>>(Wk, Wq, Wv, Wt);
  proj_kernel<<<256, 512, 0, stream>>>(x, Wt, Kb, Qb, Vt);
  attn_kernel<<<512, 256, 0, stream>>>(Kb, Qb, Vt, out);
}